// Round 5
// baseline (40.341 us; speedup 1.0000x reference)
//
#include <hip/hip_runtime.h>
#include <math.h>

#define B_ 32
#define P_ 1000
#define T_ 16
#define D_ 78
#define O_ 72
#define NXB 16            // ceil(P_/64)
#define BIGC 100000000.0f

// ---------------- K1: dist & liou + per-p scalars + per-block partial maxes ----------------
// Identity: per valid element, ovr = 30-|po-to|, union = 30+|po-to|.
// S = sum(m*|po-to|), cnt = sum(m): dist = S/max(cnt,1), liou = (30c-S)/(30c+S+1e-9).
__global__ __launch_bounds__(256) void k1(
        const float* __restrict__ preds, const float* __restrict__ targets,
        const int* __restrict__ imgw_p, const int* __restrict__ imgh_p,
        float* __restrict__ dist, float* __restrict__ liou,
        float4* __restrict__ scal4, float* __restrict__ pths,
        float* __restrict__ pmax) {
    __shared__ float pred_s[64 * 81];          // pad 81 -> conflict-free per-lane rows
    __shared__ float2 tomg[T_ * O_];           // [(g*O+o)*4 + j] = (to*w, mask), t = 4g+j
    __shared__ float cnt_s[T_], clen_s[T_], ts0_s[T_], ts1_s[T_], tth_s[T_];
    __shared__ float red[256];

    const int b = blockIdx.y, bx = blockIdx.x;
    const int p0 = bx * 64;
    const int rows = min(64, P_ - p0);
    const float w = (float)(imgw_p[0] - 1);
    const float h = (float)(imgh_p[0] - 1);
    const float imgwf = (float)imgw_p[0];

    // stage preds rows (coalesced float4); scale col 3 and cols>=6 by w
    {
        const float4* gbase = (const float4*)(preds + ((size_t)b * P_ + p0) * D_);
        const int n4 = rows * D_ / 4;
        for (int i = threadIdx.x; i < n4; i += 256) {
            float4 v = gbase[i];
            int base = i * 4;
            int r = base / D_, c = base - r * D_;
#pragma unroll
            for (int k = 0; k < 4; ++k) {
                int cc = c + k, rr = r;
                if (cc >= D_) { cc -= D_; ++rr; }
                float x = (&v.x)[k];
                if (cc >= 6 || cc == 3) x *= w;
                pred_s[rr * 81 + cc] = x;
            }
        }
    }
    // stage target offsets + masks, packed per (t-group, o)
    for (int i = threadIdx.x; i < T_ * O_; i += 256) {
        int t = i / O_, o = i - t * O_;
        float to = targets[((size_t)b * T_ + t) * D_ + 6 + o] * w;
        float m = (to >= 0.f && to < imgwf) ? 1.f : 0.f;
        tomg[((t >> 2) * O_ + o) * 4 + (t & 3)] = make_float2(to, m);
    }
    __syncthreads();
    if (threadIdx.x < T_) {
        int t = threadIdx.x;
        float c = 0.f;
        for (int o = 0; o < O_; ++o) c += tomg[((t >> 2) * O_ + o) * 4 + (t & 3)].y;
        cnt_s[t] = c;
        clen_s[t] = fmaxf(c, 1.f);
        const float* tr = targets + ((size_t)b * T_ + t) * D_;
        ts0_s[t] = tr[2] * h;
        ts1_s[t] = tr[3] * w;
        tth_s[t] = tr[4];
    }
    __syncthreads();

    const int lane = threadIdx.x & 63;
    const int g = threadIdx.x >> 6;            // wave g handles t = 4g..4g+3
    const int p = p0 + lane;

    float ldm = 0.f, lsm = 0.f, ltm = 0.f;
    if (p < P_) {
        const float* lrow = pred_s + lane * 81;
        float S0 = 0.f, S1 = 0.f, S2 = 0.f, S3 = 0.f;
        const float4* tg4 = (const float4*)(tomg + (size_t)g * O_ * 4);
#pragma unroll 4
        for (int o = 0; o < O_; ++o) {
            float po = lrow[6 + o];
            float4 r0 = tg4[2 * o];            // (to0,m0,to1,m1) - wave-uniform broadcast
            float4 r1 = tg4[2 * o + 1];        // (to2,m2,to3,m3)
            S0 += r0.y * fabsf(po - r0.x);
            S1 += r0.w * fabsf(po - r0.z);
            S2 += r1.y * fabsf(po - r1.x);
            S3 += r1.w * fabsf(po - r1.z);
        }
        float Sv[4] = {S0, S1, S2, S3};
        float ps0 = lrow[2] * h, ps1 = lrow[3], pth = lrow[4];   // col3 pre-scaled by w
#pragma unroll
        for (int j = 0; j < 4; ++j) {
            int t = 4 * g + j;
            float dv = Sv[j] / clen_s[t];
            dist[(size_t)(b * T_ + t) * P_ + p] = dv;
            ldm = fmaxf(ldm, dv);
            float c30 = 30.f * cnt_s[t];
            liou[(size_t)(b * T_ + t) * P_ + p] = (c30 - Sv[j]) / (c30 + Sv[j] + 1e-9f);
            float d0 = ps0 - ts0_s[t], d1 = ps1 - ts1_s[t];
            lsm = fmaxf(lsm, sqrtf(d0 * d0 + d1 * d1));
            ltm = fmaxf(ltm, fabsf(pth - tth_s[t]) * 180.f);
        }
        // first wave also emits the per-p scalars for K2/K3
        if (g == 0) {
            float fc[2];
#pragma unroll
            for (int c = 0; c < 2; ++c) {
                float x = lrow[c];
                float pc = 1.f / (1.f + expf(-x));
                float neg = -logf(1.f - pc + 1e-12f) * 0.75f * pc * pc;
                float pos = -logf(pc + 1e-12f) * 0.25f * (1.f - pc) * (1.f - pc);
                fc[c] = pos - neg;
            }
            scal4[(size_t)b * P_ + p] = make_float4(fc[0], fc[1], ps0, ps1);
            pths[(size_t)b * P_ + p] = pth;
        }
    }

    // block max reductions -> plain stores (no atomics, no init needed)
    red[threadIdx.x] = ldm; __syncthreads();
    for (int s = 128; s; s >>= 1) {
        if (threadIdx.x < s) red[threadIdx.x] = fmaxf(red[threadIdx.x], red[threadIdx.x + s]);
        __syncthreads();
    }
    float m0 = red[0]; __syncthreads();
    red[threadIdx.x] = lsm; __syncthreads();
    for (int s = 128; s; s >>= 1) {
        if (threadIdx.x < s) red[threadIdx.x] = fmaxf(red[threadIdx.x], red[threadIdx.x + s]);
        __syncthreads();
    }
    float m1 = red[0]; __syncthreads();
    red[threadIdx.x] = ltm; __syncthreads();
    for (int s = 128; s; s >>= 1) {
        if (threadIdx.x < s) red[threadIdx.x] = fmaxf(red[threadIdx.x], red[threadIdx.x + s]);
        __syncthreads();
    }
    if (threadIdx.x == 0) {
        float* q = pmax + (size_t)(b * NXB + bx) * 3;
        q[0] = m0; q[1] = m1; q[2] = red[0];
    }
}

// ---------------- K2: one BLOCK per (b,t): cost + dynamic-k + top-4 selection ----------------
__global__ __launch_bounds__(256) void k2(
        const float* __restrict__ targets, const int* __restrict__ masks,
        const int* __restrict__ imgw_p, const int* __restrict__ imgh_p,
        const float* __restrict__ dist, const float* __restrict__ liou,
        const float4* __restrict__ scal4, const float* __restrict__ pths,
        const float* __restrict__ pmax,
        float* __restrict__ cost, int4* __restrict__ sel) {
    __shared__ float lval[4][4], cval[4][4];
    __shared__ int lidx[4][4], cidx[4][4];

    const int wid = blockIdx.x;               // (b,t)
    const int b = wid >> 4, t = wid & 15;
    const int tid = threadIdx.x;
    const int wv = tid >> 6;

    // per-batch maxes from the 16 partials (uniform -> scalar loads)
    float dm = 0.f, sm = 0.f, tm = 0.f;
    for (int i = 0; i < NXB; ++i) {
        const float* q = pmax + (size_t)(b * NXB + i) * 3;
        dm = fmaxf(dm, q[0]); sm = fmaxf(sm, q[1]); tm = fmaxf(tm, q[2]);
    }
    dm = fmaxf(dm, 1e-8f); sm = fmaxf(sm, 1e-8f); tm = fmaxf(tm, 1e-8f);

    const float w = (float)(imgw_p[0] - 1);
    const float h = (float)(imgh_p[0] - 1);
    const float* tr = targets + (size_t)(b * T_ + t) * D_;
    const float ts0 = tr[2] * h, ts1 = tr[3] * w, tth = tr[4];
    int lab = (int)tr[1]; lab = lab < 0 ? 0 : (lab > 1 ? 1 : lab);
    const int mk = masks[b * T_ + t];

    const float* drow = dist + (size_t)(b * T_ + t) * P_;
    const float* lrow = liou + (size_t)(b * T_ + t) * P_;
    float* crow = cost + (size_t)(b * T_ + t) * P_;
    const float4* s4b = scal4 + (size_t)b * P_;
    const float* ptb = pths + (size_t)b * P_;

    float lv[4], cv[4];
#pragma unroll
    for (int i = 0; i < 4; ++i) {
        int p = tid + 256 * i;
        if (p < P_) {
            float d = drow[p];
            float4 s4 = s4b[p];
            float pth = ptb[p];
            float dsc = 1.f - d / dm + 0.01f;
            float d0 = s4.z - ts0, d1 = s4.w - ts1;
            float ssc = 1.f - sqrtf(d0 * d0 + d1 * d1) / sm + 0.01f;
            float tsc = 1.f - fabsf(pth - tth) * 180.f / tm + 0.01f;
            float reg = fmaxf(dsc, 1e-3f) * fmaxf(ssc, 1e-3f) * fmaxf(tsc, 1e-3f);
            float c = -(reg * reg) * 3.f + (lab ? s4.y : s4.x);
            if (mk <= 0) c = BIGC;
            crow[p] = c;
            cv[i] = c;
            lv[i] = lrow[p];
        } else {
            cv[i] = INFINITY;
            lv[i] = -INFINITY;
        }
    }

    // per-wave top-4 liou (desc, lower-p tie-break) -> LDS
    for (int r = 0; r < 4; ++r) {
        float bv = -INFINITY; int bi = 0x7fffffff;
#pragma unroll
        for (int i = 0; i < 4; ++i) {
            if (lv[i] > bv) { bv = lv[i]; bi = tid + 256 * i; }
        }
        for (int off = 32; off; off >>= 1) {
            float ov = __shfl_xor(bv, off, 64);
            int oi = __shfl_xor(bi, off, 64);
            if (ov > bv || (ov == bv && oi < bi)) { bv = ov; bi = oi; }
        }
        if ((tid & 63) == 0) { lval[wv][r] = bv; lidx[wv][r] = bi; }
        if ((bi & 255) == tid) lv[bi >> 8] = -INFINITY;   // owner deactivates
    }
    // per-wave top-4 cost (asc, lower-p tie-break) -> LDS
    for (int r = 0; r < 4; ++r) {
        float bv = INFINITY; int bi = 0x7fffffff;
#pragma unroll
        for (int i = 0; i < 4; ++i) {
            if (cv[i] < bv) { bv = cv[i]; bi = tid + 256 * i; }
        }
        for (int off = 32; off; off >>= 1) {
            float ov = __shfl_xor(bv, off, 64);
            int oi = __shfl_xor(bi, off, 64);
            if (ov < bv || (ov == bv && oi < bi)) { bv = ov; bi = oi; }
        }
        if ((tid & 63) == 0) { cval[wv][r] = bv; cidx[wv][r] = bi; }
        if ((bi & 255) == tid) cv[bi >> 8] = INFINITY;
    }
    __syncthreads();

    if (tid == 0) {
        // merge 16 liou candidates -> top-4 desc, sum in desc order
        float sum = 0.f;
        unsigned int used = 0;
        for (int r = 0; r < 4; ++r) {
            float bv = -INFINITY; int bi = 0x7fffffff, bj = -1;
#pragma unroll
            for (int j = 0; j < 16; ++j) {
                if (used & (1u << j)) continue;
                float v = lval[j >> 2][j & 3]; int ix = lidx[j >> 2][j & 3];
                if (v > bv || (v == bv && ix < bi)) { bv = v; bi = ix; bj = j; }
            }
            used |= 1u << bj;
            sum += bv;
        }
        int dk = 0;
        if (mk > 0) {
            dk = (int)sum;            // trunc toward zero == astype(int32)
            if (dk < 1) dk = 1;
            if (dk > 4) dk = 4;
        }
        // merge 16 cost candidates -> top-4 asc
        int selp[4];
        used = 0;
        for (int r = 0; r < 4; ++r) {
            float bv = INFINITY; int bi = 0x7fffffff, bj = -1;
#pragma unroll
            for (int j = 0; j < 16; ++j) {
                if (used & (1u << j)) continue;
                float v = cval[j >> 2][j & 3]; int ix = cidx[j >> 2][j & 3];
                if (v < bv || (v == bv && ix < bi)) { bv = v; bi = ix; bj = j; }
            }
            used |= 1u << bj;
            selp[r] = bi;
        }
        sel[wid] = make_int4(dk > 0 ? selp[0] : -1, dk > 1 ? selp[1] : -1,
                             dk > 2 ? selp[2] : -1, dk > 3 ? selp[3] : -1);
    }
}

// ---------------- K3: membership + conflict resolution + output ----------------
__global__ __launch_bounds__(256) void k3(const int4* __restrict__ sel,
                                          const float* __restrict__ cost,
                                          int* __restrict__ out) {
    __shared__ int selE[64];
    const int b = blockIdx.x;
    if (threadIdx.x < 64) selE[threadIdx.x] = ((const int*)sel)[b * 64 + threadIdx.x];
    __syncthreads();

#pragma unroll
    for (int k = 0; k < 4; ++k) {
        int p = k * 256 + threadIdx.x;
        if (p >= P_) continue;
        unsigned int m = 0;
#pragma unroll
        for (int t = 0; t < T_; ++t) {
            bool hit = (selE[4 * t] == p) | (selE[4 * t + 1] == p) |
                       (selE[4 * t + 2] == p) | (selE[4 * t + 3] == p);
            if (hit) m |= 1u << t;
        }
        int matched = -1;
        if (m) {
            if (__popc(m) == 1) {
                matched = __ffs(m) - 1;
            } else {
                float best = INFINITY;
#pragma unroll
                for (int t = 0; t < T_; ++t) {
                    if ((m >> t) & 1u) {
                        float c = cost[(size_t)(b * T_ + t) * P_ + p];
                        if (c < best) { best = c; matched = t; }  // strict <: first-min
                    }
                }
            }
        }
        out[b * P_ + p] = (matched >= 0) ? 1 : 0;
        out[B_ * P_ + b * P_ + p] = matched;
    }
}

extern "C" void kernel_launch(void* const* d_in, const int* in_sizes, int n_in,
                              void* d_out, int out_size, void* d_ws, size_t ws_size,
                              hipStream_t stream) {
    const float* preds   = (const float*)d_in[0];
    const float* targets = (const float*)d_in[1];
    const int*   masks   = (const int*)d_in[2];
    const int*   imgw    = (const int*)d_in[3];
    const int*   imgh    = (const int*)d_in[4];
    int* out = (int*)d_out;

    char* ws = (char*)d_ws;
    const size_t SZ = (size_t)B_ * T_ * P_ * sizeof(float);     // 2,048,000 B
    float*  dist  = (float*)ws;                                  // [B][T][P]
    float*  liou  = (float*)(ws + SZ);                           // [B][T][P]
    float*  cost  = (float*)(ws + 2 * SZ);                       // [B][T][P]
    float4* scal4 = (float4*)(ws + 3 * SZ);                      // [B][P] {fc0,fc1,ps0,ps1}
    float*  pths  = (float*)(ws + 3 * SZ + (size_t)B_ * P_ * 16);// [B][P]
    float*  pmax  = (float*)(ws + 3 * SZ + (size_t)B_ * P_ * 20);// [B][NXB][3]
    int4*   sel   = (int4*)(ws + 3 * SZ + (size_t)B_ * P_ * 20 + (size_t)B_ * NXB * 3 * 4 + 64);

    k1<<<dim3(NXB, B_), 256, 0, stream>>>(preds, targets, imgw, imgh, dist, liou, scal4, pths, pmax);
    k2<<<B_ * T_, 256, 0, stream>>>(targets, masks, imgw, imgh, dist, liou, scal4, pths, pmax, cost, sel);
    k3<<<B_, 256, 0, stream>>>(sel, cost, out);
}

// Round 6
// 37.603 us; speedup vs baseline: 1.0728x; 1.0728x over previous
//
#include <hip/hip_runtime.h>
#include <math.h>

#define B_ 32
#define P_ 1000
#define T_ 16
#define D_ 78
#define O_ 72
#define NXB 16            // p-chunks of 64
#define BIGC 100000000.0f

// ---------------- K1: dist & liou + per-p scalars + per-block partial maxes ----------------
// 1024 threads = 16 waves = 4 t-groups x 4 o-quarters, over 64 p's.
// Identity: per valid element, ovr = 30-|po-to|, union = 30+|po-to|.
// S = sum(m*|po-to|), cnt = sum(m): dist = S/max(cnt,1), liou = (30c-S)/(30c+S+1e-9).
__global__ __launch_bounds__(1024, 8) void k1(
        const float* __restrict__ preds, const float* __restrict__ targets,
        const int* __restrict__ imgw_p, const int* __restrict__ imgh_p,
        float* __restrict__ dist, float* __restrict__ liou,
        float4* __restrict__ scal4, float* __restrict__ pths,
        float* __restrict__ pmax) {
    __shared__ float pred_s[64 * 81];          // 20.7KB, pad 81 -> conflict-free rows
    __shared__ float2 tomg[T_ * O_];           // 9.2KB  [(t>>2)*O+o]*4 + (t&3)] = (to*w, m)
    __shared__ float Spart[T_][4][64];         // 16KB   partial sums per o-quarter
    __shared__ float wmax[16][3];
    __shared__ float cnt_s[T_], clen_s[T_], ts0_s[T_], ts1_s[T_], tth_s[T_];

    const int b = blockIdx.y, bx = blockIdx.x;
    const int p0 = bx * 64;
    const int rows = min(64, P_ - p0);
    const int tid = threadIdx.x;
    const float w = (float)(imgw_p[0] - 1);
    const float h = (float)(imgh_p[0] - 1);
    const float imgwf = (float)imgw_p[0];

    // stage preds rows (coalesced float4); scale col 3 and cols>=6 by w
    {
        const float4* gbase = (const float4*)(preds + ((size_t)b * P_ + p0) * D_);
        const int n4 = rows * D_ / 4;
        for (int i = tid; i < n4; i += 1024) {
            float4 v = gbase[i];
            int base = i * 4;
            int r = base / D_, c = base - r * D_;
#pragma unroll
            for (int k = 0; k < 4; ++k) {
                int cc = c + k, rr = r;
                if (cc >= D_) { cc -= D_; ++rr; }
                float x = (&v.x)[k];
                if (cc >= 6 || cc == 3) x *= w;
                pred_s[rr * 81 + cc] = x;
            }
        }
    }
    // stage target offsets + masks, packed per (t-group, o)
    for (int i = tid; i < T_ * O_; i += 1024) {
        int t = i / O_, o = i - t * O_;
        float to = targets[((size_t)b * T_ + t) * D_ + 6 + o] * w;
        float m = (to >= 0.f && to < imgwf) ? 1.f : 0.f;
        tomg[((t >> 2) * O_ + o) * 4 + (t & 3)] = make_float2(to, m);
    }
    __syncthreads();
    if (tid < T_) {
        int t = tid;
        float c = 0.f;
        for (int o = 0; o < O_; ++o) c += tomg[((t >> 2) * O_ + o) * 4 + (t & 3)].y;
        cnt_s[t] = c;
        clen_s[t] = fmaxf(c, 1.f);
        const float* tr = targets + ((size_t)b * T_ + t) * D_;
        ts0_s[t] = tr[2] * h;
        ts1_s[t] = tr[3] * w;
        tth_s[t] = tr[4];
    }
    __syncthreads();

    // ---- phase 1: partial masked-L1 sums, 18 o's per wave ----
    {
        const int lane = tid & 63;
        const int wv = tid >> 6;          // 0..15
        const int tg = wv & 3;            // t-group: t = 4tg..4tg+3
        const int oq = wv >> 2;           // o-quarter
        const float* lrow = pred_s + lane * 81;
        const float4* tg4 = (const float4*)(tomg + (size_t)tg * O_ * 4);
        const int o_lo = oq * 18;
        float S0 = 0.f, S1 = 0.f, S2 = 0.f, S3 = 0.f;
#pragma unroll
        for (int i = 0; i < 18; ++i) {
            int o = o_lo + i;
            float po = lrow[6 + o];
            float4 r0 = tg4[2 * o];        // (to0,m0,to1,m1) wave-uniform broadcast
            float4 r1 = tg4[2 * o + 1];    // (to2,m2,to3,m3)
            S0 += r0.y * fabsf(po - r0.x);
            S1 += r0.w * fabsf(po - r0.z);
            S2 += r1.y * fabsf(po - r1.x);
            S3 += r1.w * fabsf(po - r1.z);
        }
        Spart[4 * tg + 0][oq][lane] = S0;
        Spart[4 * tg + 1][oq][lane] = S1;
        Spart[4 * tg + 2][oq][lane] = S2;
        Spart[4 * tg + 3][oq][lane] = S3;
    }
    __syncthreads();

    // ---- phase 2: combine quarters; thread = (t, p) ----
    const int th = tid >> 6, pl = tid & 63;
    const int p = p0 + pl;
    float ldm = 0.f, lsm = 0.f, ltm = 0.f;
    if (pl < rows) {
        float S = ((Spart[th][0][pl] + Spart[th][1][pl]) + Spart[th][2][pl]) + Spart[th][3][pl];
        float dv = S / clen_s[th];
        dist[(size_t)(b * T_ + th) * P_ + p] = dv;
        ldm = dv;
        float c30 = 30.f * cnt_s[th];
        liou[(size_t)(b * T_ + th) * P_ + p] = (c30 - S) / (c30 + S + 1e-9f);
        const float* prow = pred_s + pl * 81;
        float ps0 = prow[2] * h, ps1 = prow[3], pth = prow[4];   // col3 pre-scaled by w
        float d0 = ps0 - ts0_s[th], d1 = ps1 - ts1_s[th];
        lsm = sqrtf(d0 * d0 + d1 * d1);
        ltm = fabsf(pth - tth_s[th]) * 180.f;
        if (th == 0) {                    // per-p scalars for K2
            float fc[2];
#pragma unroll
            for (int c = 0; c < 2; ++c) {
                float x = prow[c];
                float pc = 1.f / (1.f + expf(-x));
                float neg = -logf(1.f - pc + 1e-12f) * 0.75f * pc * pc;
                float pos = -logf(pc + 1e-12f) * 0.25f * (1.f - pc) * (1.f - pc);
                fc[c] = pos - neg;
            }
            scal4[(size_t)b * P_ + p] = make_float4(fc[0], fc[1], ps0, ps1);
            pths[(size_t)b * P_ + p] = pth;
        }
    }

    // ---- per-wave shuffle max, then thread-0 merge (exact: fmax is order-invariant) ----
    for (int off = 32; off; off >>= 1) {
        ldm = fmaxf(ldm, __shfl_xor(ldm, off, 64));
        lsm = fmaxf(lsm, __shfl_xor(lsm, off, 64));
        ltm = fmaxf(ltm, __shfl_xor(ltm, off, 64));
    }
    if (pl == 0) { wmax[th][0] = ldm; wmax[th][1] = lsm; wmax[th][2] = ltm; }
    __syncthreads();
    if (tid == 0) {
        float m0 = 0.f, m1 = 0.f, m2 = 0.f;
#pragma unroll
        for (int i = 0; i < 16; ++i) {
            m0 = fmaxf(m0, wmax[i][0]);
            m1 = fmaxf(m1, wmax[i][1]);
            m2 = fmaxf(m2, wmax[i][2]);
        }
        float* q = pmax + (size_t)(b * NXB + bx) * 3;
        q[0] = m0; q[1] = m1; q[2] = m2;
    }
}

// ---------------- K2 (fused k2+k3): one block per batch ----------------
// Phase 1: wave w = target t: cost + dynamic-k + top-4 selection (round-4 proven code).
// Phase 2: thread = p: membership mask + conflict resolution + output.
__global__ __launch_bounds__(1024) void k2(
        const float* __restrict__ targets, const int* __restrict__ masks,
        const int* __restrict__ imgw_p, const int* __restrict__ imgh_p,
        const float* __restrict__ dist, const float* __restrict__ liou,
        const float4* __restrict__ scal4, const float* __restrict__ pths,
        const float* __restrict__ pmax,
        float* __restrict__ cost, int* __restrict__ out) {
    __shared__ int selE[64];

    const int b = blockIdx.x;
    const int tid = threadIdx.x;
    const int t = tid >> 6;          // wave = target
    const int lane = tid & 63;

    // per-batch maxes from the 16 partials (uniform -> scalar loads)
    float dm = 0.f, sm = 0.f, tm = 0.f;
    for (int i = 0; i < NXB; ++i) {
        const float* q = pmax + (size_t)(b * NXB + i) * 3;
        dm = fmaxf(dm, q[0]); sm = fmaxf(sm, q[1]); tm = fmaxf(tm, q[2]);
    }
    dm = fmaxf(dm, 1e-8f); sm = fmaxf(sm, 1e-8f); tm = fmaxf(tm, 1e-8f);

    const float w = (float)(imgw_p[0] - 1);
    const float h = (float)(imgh_p[0] - 1);
    const float* tr = targets + (size_t)(b * T_ + t) * D_;
    const float ts0 = tr[2] * h, ts1 = tr[3] * w, tth = tr[4];
    int lab = (int)tr[1]; lab = lab < 0 ? 0 : (lab > 1 ? 1 : lab);
    const int mk = masks[b * T_ + t];

    const float* drow = dist + (size_t)(b * T_ + t) * P_;
    const float* lrow = liou + (size_t)(b * T_ + t) * P_;
    float* crow = cost + (size_t)(b * T_ + t) * P_;
    const float4* s4b = scal4 + (size_t)b * P_;
    const float* ptb = pths + (size_t)b * P_;

    float lv[16], cv[16];
#pragma unroll
    for (int i = 0; i < 16; ++i) {
        int p = lane + 64 * i;
        if (p < P_) {
            float d = drow[p];
            float4 s4 = s4b[p];
            float pth = ptb[p];
            float dsc = 1.f - d / dm + 0.01f;
            float d0 = s4.z - ts0, d1 = s4.w - ts1;
            float ssc = 1.f - sqrtf(d0 * d0 + d1 * d1) / sm + 0.01f;
            float tsc = 1.f - fabsf(pth - tth) * 180.f / tm + 0.01f;
            float reg = fmaxf(dsc, 1e-3f) * fmaxf(ssc, 1e-3f) * fmaxf(tsc, 1e-3f);
            float c = -(reg * reg) * 3.f + (lab ? s4.y : s4.x);
            if (mk <= 0) c = BIGC;
            crow[p] = c;
            cv[i] = c;
            lv[i] = lrow[p];
        } else {
            cv[i] = INFINITY;
            lv[i] = -INFINITY;
        }
    }

    // sum of top-4 liou (wave argmax, 4 rounds, desc order)
    float sum = 0.f;
    for (int r = 0; r < 4; ++r) {
        float bv = -INFINITY; int bi = 0x7fffffff;
#pragma unroll
        for (int i = 0; i < 16; ++i) {
            if (lv[i] > bv) { bv = lv[i]; bi = lane + 64 * i; }
        }
        for (int off = 32; off; off >>= 1) {
            float ov = __shfl_xor(bv, off, 64);
            int oi = __shfl_xor(bi, off, 64);
            if (ov > bv || (ov == bv && oi < bi)) { bv = ov; bi = oi; }
        }
        sum += bv;
        if ((bi & 63) == lane) lv[bi >> 6] = -INFINITY;
    }
    int dk = 0;
    if (mk > 0) {
        dk = (int)sum;                // trunc toward zero == astype(int32)
        if (dk < 1) dk = 1;
        if (dk > 4) dk = 4;
    }

    // top-4 lowest cost, tie-break lower p (lax.top_k stable semantics)
    int selp[4];
#pragma unroll
    for (int r = 0; r < 4; ++r) {
        float bv = INFINITY; int bi = 0x7fffffff;
#pragma unroll
        for (int i = 0; i < 16; ++i) {
            if (cv[i] < bv) { bv = cv[i]; bi = lane + 64 * i; }
        }
        for (int off = 32; off; off >>= 1) {
            float ov = __shfl_xor(bv, off, 64);
            int oi = __shfl_xor(bi, off, 64);
            if (ov < bv || (ov == bv && oi < bi)) { bv = ov; bi = oi; }
        }
        selp[r] = bi;
        if ((bi & 63) == lane) cv[bi >> 6] = INFINITY;
    }

    if (lane == 0) {
#pragma unroll
        for (int j = 0; j < 4; ++j) selE[4 * t + j] = (j < dk) ? selp[j] : -1;
    }
    __syncthreads();   // selE visible; crow global writes drained (vmcnt(0) before barrier)

    // ---- phase 2: conflict resolution + output (thread = p) ----
    if (tid < P_) {
        const int p = tid;
        unsigned int m = 0;
#pragma unroll
        for (int t2 = 0; t2 < T_; ++t2) {
            bool hit = (selE[4 * t2] == p) | (selE[4 * t2 + 1] == p) |
                       (selE[4 * t2 + 2] == p) | (selE[4 * t2 + 3] == p);
            if (hit) m |= 1u << t2;
        }
        int matched = -1;
        if (m) {
            if (__popc(m) == 1) {
                matched = __ffs(m) - 1;
            } else {
                float best = INFINITY;
#pragma unroll
                for (int t2 = 0; t2 < T_; ++t2) {
                    if ((m >> t2) & 1u) {
                        float c = cost[(size_t)(b * T_ + t2) * P_ + p];
                        if (c < best) { best = c; matched = t2; }  // strict <: first-min
                    }
                }
            }
        }
        out[b * P_ + p] = (matched >= 0) ? 1 : 0;
        out[B_ * P_ + b * P_ + p] = matched;
    }
}

extern "C" void kernel_launch(void* const* d_in, const int* in_sizes, int n_in,
                              void* d_out, int out_size, void* d_ws, size_t ws_size,
                              hipStream_t stream) {
    const float* preds   = (const float*)d_in[0];
    const float* targets = (const float*)d_in[1];
    const int*   masks   = (const int*)d_in[2];
    const int*   imgw    = (const int*)d_in[3];
    const int*   imgh    = (const int*)d_in[4];
    int* out = (int*)d_out;

    char* ws = (char*)d_ws;
    const size_t SZ = (size_t)B_ * T_ * P_ * sizeof(float);     // 2,048,000 B
    float*  dist  = (float*)ws;                                  // [B][T][P]
    float*  liou  = (float*)(ws + SZ);                           // [B][T][P]
    float*  cost  = (float*)(ws + 2 * SZ);                       // [B][T][P]
    float4* scal4 = (float4*)(ws + 3 * SZ);                      // [B][P] {fc0,fc1,ps0,ps1}
    float*  pths  = (float*)(ws + 3 * SZ + (size_t)B_ * P_ * 16);// [B][P]
    float*  pmax  = (float*)(ws + 3 * SZ + (size_t)B_ * P_ * 20);// [B][NXB][3]

    k1<<<dim3(NXB, B_), 1024, 0, stream>>>(preds, targets, imgw, imgh, dist, liou, scal4, pths, pmax);
    k2<<<B_, 1024, 0, stream>>>(targets, masks, imgw, imgh, dist, liou, scal4, pths, pmax, cost, out);
}

// Round 7
// 36.608 us; speedup vs baseline: 1.1020x; 1.0272x over previous
//
#include <hip/hip_runtime.h>
#include <math.h>

#define B_ 32
#define P_ 1000
#define T_ 16
#define D_ 78
#define O_ 72
#define NXB 16            // p-chunks of 64
#define BIGC 100000000.0f

// ---------------- K1: dist & liou + per-p scalars + per-block partial maxes ----------------
// 1024 threads = 16 waves = 4 t-groups x 4 o-quarters, over 64 p's.
// Identity: per valid element, ovr = 30-|po-to|, union = 30+|po-to|.
// S = sum(m*|po-to|), cnt = sum(m): dist = S/max(cnt,1), liou = (30c-S)/(30c+S+1e-9).
__global__ __launch_bounds__(1024, 8) void k1(
        const float* __restrict__ preds, const float* __restrict__ targets,
        const int* __restrict__ imgw_p, const int* __restrict__ imgh_p,
        float* __restrict__ dist, float* __restrict__ liou,
        float4* __restrict__ scal4, float* __restrict__ pths,
        float* __restrict__ pmax) {
    __shared__ float pred_s[64 * 81];          // 20.7KB, pad 81 -> conflict-free rows
    __shared__ float2 tomg[T_ * O_];           // 9.2KB  [((t>>2)*O+o)*4 + (t&3)] = (to*w, m)
    __shared__ float Spart[T_][4][64];         // 16KB   partial sums per o-quarter
    __shared__ float wmax[16][3];
    __shared__ float cnt_s[T_], clen_s[T_], ts0_s[T_], ts1_s[T_], tth_s[T_];

    const int b = blockIdx.y, bx = blockIdx.x;
    const int p0 = bx * 64;
    const int rows = min(64, P_ - p0);
    const int tid = threadIdx.x;
    const float w = (float)(imgw_p[0] - 1);
    const float h = (float)(imgh_p[0] - 1);
    const float imgwf = (float)imgw_p[0];

    // stage preds rows (coalesced float4); scale col 3 and cols>=6 by w
    {
        const float4* gbase = (const float4*)(preds + ((size_t)b * P_ + p0) * D_);
        const int n4 = rows * D_ / 4;
        for (int i = tid; i < n4; i += 1024) {
            float4 v = gbase[i];
            int base = i * 4;
            int r = base / D_, c = base - r * D_;
#pragma unroll
            for (int k = 0; k < 4; ++k) {
                int cc = c + k, rr = r;
                if (cc >= D_) { cc -= D_; ++rr; }
                float x = (&v.x)[k];
                if (cc >= 6 || cc == 3) x *= w;
                pred_s[rr * 81 + cc] = x;
            }
        }
    }
    // stage target offsets + masks, packed per (t-group, o)
    for (int i = tid; i < T_ * O_; i += 1024) {
        int t = i / O_, o = i - t * O_;
        float to = targets[((size_t)b * T_ + t) * D_ + 6 + o] * w;
        float m = (to >= 0.f && to < imgwf) ? 1.f : 0.f;
        tomg[((t >> 2) * O_ + o) * 4 + (t & 3)] = make_float2(to, m);
    }
    __syncthreads();
    if (tid < T_) {
        int t = tid;
        float c = 0.f;
        for (int o = 0; o < O_; ++o) c += tomg[((t >> 2) * O_ + o) * 4 + (t & 3)].y;
        cnt_s[t] = c;
        clen_s[t] = fmaxf(c, 1.f);
        const float* tr = targets + ((size_t)b * T_ + t) * D_;
        ts0_s[t] = tr[2] * h;
        ts1_s[t] = tr[3] * w;
        tth_s[t] = tr[4];
    }
    __syncthreads();

    // ---- phase 1: partial masked-L1 sums, 18 o's per wave ----
    {
        const int lane = tid & 63;
        const int wv = tid >> 6;          // 0..15
        const int tg = wv & 3;            // t-group: t = 4tg..4tg+3
        const int oq = wv >> 2;           // o-quarter
        const float* lrow = pred_s + lane * 81;
        const float4* tg4 = (const float4*)(tomg + (size_t)tg * O_ * 4);
        const int o_lo = oq * 18;
        float S0 = 0.f, S1 = 0.f, S2 = 0.f, S3 = 0.f;
#pragma unroll
        for (int i = 0; i < 18; ++i) {
            int o = o_lo + i;
            float po = lrow[6 + o];
            float4 r0 = tg4[2 * o];        // (to0,m0,to1,m1) wave-uniform broadcast
            float4 r1 = tg4[2 * o + 1];    // (to2,m2,to3,m3)
            S0 += r0.y * fabsf(po - r0.x);
            S1 += r0.w * fabsf(po - r0.z);
            S2 += r1.y * fabsf(po - r1.x);
            S3 += r1.w * fabsf(po - r1.z);
        }
        Spart[4 * tg + 0][oq][lane] = S0;
        Spart[4 * tg + 1][oq][lane] = S1;
        Spart[4 * tg + 2][oq][lane] = S2;
        Spart[4 * tg + 3][oq][lane] = S3;
    }
    __syncthreads();

    // ---- phase 2: combine quarters; thread = (t, p) ----
    const int th = tid >> 6, pl = tid & 63;
    const int p = p0 + pl;
    float ldm = 0.f, lsm = 0.f, ltm = 0.f;
    if (pl < rows) {
        float S = ((Spart[th][0][pl] + Spart[th][1][pl]) + Spart[th][2][pl]) + Spart[th][3][pl];
        float dv = S / clen_s[th];
        dist[(size_t)(b * T_ + th) * P_ + p] = dv;
        ldm = dv;
        float c30 = 30.f * cnt_s[th];
        liou[(size_t)(b * T_ + th) * P_ + p] = (c30 - S) / (c30 + S + 1e-9f);
        const float* prow = pred_s + pl * 81;
        float ps0 = prow[2] * h, ps1 = prow[3], pth = prow[4];   // col3 pre-scaled by w
        float d0 = ps0 - ts0_s[th], d1 = ps1 - ts1_s[th];
        lsm = sqrtf(d0 * d0 + d1 * d1);
        ltm = fabsf(pth - tth_s[th]) * 180.f;
        if (th == 0) {                    // per-p scalars for K2
            float fc[2];
#pragma unroll
            for (int c = 0; c < 2; ++c) {
                float x = prow[c];
                float pc = 1.f / (1.f + expf(-x));
                float neg = -logf(1.f - pc + 1e-12f) * 0.75f * pc * pc;
                float pos = -logf(pc + 1e-12f) * 0.25f * (1.f - pc) * (1.f - pc);
                fc[c] = pos - neg;
            }
            scal4[(size_t)b * P_ + p] = make_float4(fc[0], fc[1], ps0, ps1);
            pths[(size_t)b * P_ + p] = pth;
        }
    }

    // ---- per-wave shuffle max, then thread-0 merge (exact: fmax is order-invariant) ----
    for (int off = 32; off; off >>= 1) {
        ldm = fmaxf(ldm, __shfl_xor(ldm, off, 64));
        lsm = fmaxf(lsm, __shfl_xor(lsm, off, 64));
        ltm = fmaxf(ltm, __shfl_xor(ltm, off, 64));
    }
    if (pl == 0) { wmax[th][0] = ldm; wmax[th][1] = lsm; wmax[th][2] = ltm; }
    __syncthreads();
    if (tid == 0) {
        float m0 = 0.f, m1 = 0.f, m2 = 0.f;
#pragma unroll
        for (int i = 0; i < 16; ++i) {
            m0 = fmaxf(m0, wmax[i][0]);
            m1 = fmaxf(m1, wmax[i][1]);
            m2 = fmaxf(m2, wmax[i][2]);
        }
        float* q = pmax + (size_t)(b * NXB + bx) * 3;
        q[0] = m0; q[1] = m1; q[2] = m2;
    }
}

// ---------------- K2 (fused): one block per batch ----------------
// Phase 1: wave = target t: cost (to LDS) + dynamic-k + top-4 selection.
// Phase 2: thread = p: membership mask + conflict resolution + output.
// NOTE: lv/cv deactivation uses compile-time indices (compare vs bi) so the
// arrays live in VGPRs, not scratch (rule #20 — runtime index => localMem).
__global__ __launch_bounds__(1024) void k2(
        const float* __restrict__ targets, const int* __restrict__ masks,
        const int* __restrict__ imgw_p, const int* __restrict__ imgh_p,
        const float* __restrict__ dist, const float* __restrict__ liou,
        const float4* __restrict__ scal4, const float* __restrict__ pths,
        const float* __restrict__ pmax,
        int* __restrict__ out) {
    __shared__ float costL[T_][P_];   // 64 KB
    __shared__ int selE[64];

    const int b = blockIdx.x;
    const int tid = threadIdx.x;
    const int t = tid >> 6;          // wave = target
    const int lane = tid & 63;

    // per-batch maxes from the 16 partials (uniform -> scalar loads)
    float dm = 0.f, sm = 0.f, tm = 0.f;
    for (int i = 0; i < NXB; ++i) {
        const float* q = pmax + (size_t)(b * NXB + i) * 3;
        dm = fmaxf(dm, q[0]); sm = fmaxf(sm, q[1]); tm = fmaxf(tm, q[2]);
    }
    dm = fmaxf(dm, 1e-8f); sm = fmaxf(sm, 1e-8f); tm = fmaxf(tm, 1e-8f);

    const float w = (float)(imgw_p[0] - 1);
    const float h = (float)(imgh_p[0] - 1);
    const float* tr = targets + (size_t)(b * T_ + t) * D_;
    const float ts0 = tr[2] * h, ts1 = tr[3] * w, tth = tr[4];
    int lab = (int)tr[1]; lab = lab < 0 ? 0 : (lab > 1 ? 1 : lab);
    const int mk = masks[b * T_ + t];

    const float* drow = dist + (size_t)(b * T_ + t) * P_;
    const float* lrow = liou + (size_t)(b * T_ + t) * P_;
    const float4* s4b = scal4 + (size_t)b * P_;
    const float* ptb = pths + (size_t)b * P_;

    float lv[16], cv[16];
#pragma unroll
    for (int i = 0; i < 16; ++i) {
        int p = lane + 64 * i;
        if (p < P_) {
            float d = drow[p];
            float4 s4 = s4b[p];
            float pth = ptb[p];
            float dsc = 1.f - d / dm + 0.01f;
            float d0 = s4.z - ts0, d1 = s4.w - ts1;
            float ssc = 1.f - sqrtf(d0 * d0 + d1 * d1) / sm + 0.01f;
            float tsc = 1.f - fabsf(pth - tth) * 180.f / tm + 0.01f;
            float reg = fmaxf(dsc, 1e-3f) * fmaxf(ssc, 1e-3f) * fmaxf(tsc, 1e-3f);
            float c = -(reg * reg) * 3.f + (lab ? s4.y : s4.x);
            if (mk <= 0) c = BIGC;
            costL[t][p] = c;
            cv[i] = c;
            lv[i] = lrow[p];
        } else {
            cv[i] = INFINITY;
            lv[i] = -INFINITY;
        }
    }

    // sum of top-4 liou (wave argmax, 4 rounds, desc order)
    float sum = 0.f;
    for (int r = 0; r < 4; ++r) {
        float bv = -INFINITY; int bi = 0x7fffffff;
#pragma unroll
        for (int i = 0; i < 16; ++i) {
            if (lv[i] > bv) { bv = lv[i]; bi = lane + 64 * i; }
        }
        for (int off = 32; off; off >>= 1) {
            float ov = __shfl_xor(bv, off, 64);
            int oi = __shfl_xor(bi, off, 64);
            if (ov > bv || (ov == bv && oi < bi)) { bv = ov; bi = oi; }
        }
        sum += bv;
#pragma unroll
        for (int i = 0; i < 16; ++i)          // compile-time index: stays in VGPRs
            if (bi == lane + 64 * i) lv[i] = -INFINITY;
    }
    int dk = 0;
    if (mk > 0) {
        dk = (int)sum;                // trunc toward zero == astype(int32)
        if (dk < 1) dk = 1;
        if (dk > 4) dk = 4;
    }

    // top-4 lowest cost, tie-break lower p (lax.top_k stable semantics)
    int selp[4];
#pragma unroll
    for (int r = 0; r < 4; ++r) {
        float bv = INFINITY; int bi = 0x7fffffff;
#pragma unroll
        for (int i = 0; i < 16; ++i) {
            if (cv[i] < bv) { bv = cv[i]; bi = lane + 64 * i; }
        }
        for (int off = 32; off; off >>= 1) {
            float ov = __shfl_xor(bv, off, 64);
            int oi = __shfl_xor(bi, off, 64);
            if (ov < bv || (ov == bv && oi < bi)) { bv = ov; bi = oi; }
        }
        selp[r] = bi;
#pragma unroll
        for (int i = 0; i < 16; ++i)          // compile-time index: stays in VGPRs
            if (bi == lane + 64 * i) cv[i] = INFINITY;
    }

    if (lane == 0) {
#pragma unroll
        for (int j = 0; j < 4; ++j) selE[4 * t + j] = (j < dk) ? selp[j] : -1;
    }
    __syncthreads();

    // ---- phase 2: conflict resolution + output (thread = p) ----
    if (tid < P_) {
        const int p = tid;
        unsigned int m = 0;
#pragma unroll
        for (int t2 = 0; t2 < T_; ++t2) {
            bool hit = (selE[4 * t2] == p) | (selE[4 * t2 + 1] == p) |
                       (selE[4 * t2 + 2] == p) | (selE[4 * t2 + 3] == p);
            if (hit) m |= 1u << t2;
        }
        int matched = -1;
        if (m) {
            if (__popc(m) == 1) {
                matched = __ffs(m) - 1;
            } else {
                float best = INFINITY;
#pragma unroll
                for (int t2 = 0; t2 < T_; ++t2) {
                    if ((m >> t2) & 1u) {
                        float c = costL[t2][p];
                        if (c < best) { best = c; matched = t2; }  // strict <: first-min
                    }
                }
            }
        }
        out[b * P_ + p] = (matched >= 0) ? 1 : 0;
        out[B_ * P_ + b * P_ + p] = matched;
    }
}

extern "C" void kernel_launch(void* const* d_in, const int* in_sizes, int n_in,
                              void* d_out, int out_size, void* d_ws, size_t ws_size,
                              hipStream_t stream) {
    const float* preds   = (const float*)d_in[0];
    const float* targets = (const float*)d_in[1];
    const int*   masks   = (const int*)d_in[2];
    const int*   imgw    = (const int*)d_in[3];
    const int*   imgh    = (const int*)d_in[4];
    int* out = (int*)d_out;

    char* ws = (char*)d_ws;
    const size_t SZ = (size_t)B_ * T_ * P_ * sizeof(float);     // 2,048,000 B
    float*  dist  = (float*)ws;                                  // [B][T][P]
    float*  liou  = (float*)(ws + SZ);                           // [B][T][P]
    float4* scal4 = (float4*)(ws + 2 * SZ);                      // [B][P] {fc0,fc1,ps0,ps1}
    float*  pths  = (float*)(ws + 2 * SZ + (size_t)B_ * P_ * 16);// [B][P]
    float*  pmax  = (float*)(ws + 2 * SZ + (size_t)B_ * P_ * 20);// [B][NXB][3]

    k1<<<dim3(NXB, B_), 1024, 0, stream>>>(preds, targets, imgw, imgh, dist, liou, scal4, pths, pmax);
    k2<<<B_, 1024, 0, stream>>>(targets, masks, imgw, imgh, dist, liou, scal4, pths, pmax, out);
}